// Round 7
// baseline (197.527 us; speedup 1.0000x reference)
//
#include <hip/hip_runtime.h>
#include <math.h>
#include <float.h>

#define DDIM 1024   // D
#define PDIM 32     // pattern_dim
#define NPAT 256    // n_patterns
#define TOPK 4
#define BLOCK 256
#define GT   16     // tokens per tile
#define HT   8      // tokens per proj block (tile split in 2)
#define DCHP 128    // d-chunk
#define NCHP 8      // d-chunks (DDIM/DCHP)
#define RTPB 4      // tokens per route block (one per wave)

// ---------------------------------------------------------------------------
// K0 (R12, validated in the 186 us run): routing, one WAVE per token,
// hasher_w staged in LDS per 256-d segment, lane-0 atomics into gcount.
__global__ __launch_bounds__(BLOCK) void route_kernel(
    const float* __restrict__ x,
    const float* __restrict__ hasher_w,   // [PDIM, DDIM]
    const float* __restrict__ keys,       // [NPAT, PDIM]
    int*   __restrict__ tki,              // [ntok, TOPK]
    float* __restrict__ tkw,              // [ntok, TOPK]
    int*   __restrict__ gcount,           // [NPAT], pre-zeroed
    int ntok)
{
    __shared__ float shmem[RTPB * 64 * 33];   // 33.8 KB dual-purpose
    __shared__ float h_s[RTPB][32];

    const int tid  = threadIdx.x;
    const int wv   = tid >> 6;
    const int lane = tid & 63;
    const int traw = blockIdx.x * RTPB + wv;
    const int tok  = min(traw, ntok - 1);

    const float4* xrow = (const float4*)(x + (size_t)tok * DDIM);
    float4 xr[4];
    #pragma unroll
    for (int i = 0; i < 4; ++i) xr[i] = xrow[i * 64 + lane];

    float part[PDIM];
    #pragma unroll
    for (int pp = 0; pp < PDIM; ++pp) part[pp] = 0.f;

    float* hs = shmem;
    for (int i = 0; i < 4; ++i) {
        #pragma unroll
        for (int k = 0; k < 8; ++k) {
            const int q  = k * 256 + tid;
            const int pp = q >> 6, fi = q & 63;
            ((float4*)hs)[q] =
                *(const float4*)(hasher_w + (size_t)pp * DDIM + i * 256 + fi * 4);
        }
        __syncthreads();
        #pragma unroll
        for (int pp = 0; pp < PDIM; ++pp) {
            const float4 w4 = *(const float4*)&hs[pp * 256 + lane * 4];
            part[pp] = fmaf(xr[i].x, w4.x, part[pp]);
            part[pp] = fmaf(xr[i].y, w4.y, part[pp]);
            part[pp] = fmaf(xr[i].z, w4.z, part[pp]);
            part[pp] = fmaf(xr[i].w, w4.w, part[pp]);
        }
        __syncthreads();
    }

    float* P = shmem + wv * (64 * 33);
    #pragma unroll
    for (int pp = 0; pp < PDIM; ++pp) P[lane * 33 + pp] = part[pp];
    __syncthreads();

    {
        const int pp = lane & 31, half = lane >> 5;
        float hsum = 0.f;
        #pragma unroll 8
        for (int i = 0; i < 32; ++i)
            hsum += P[(half * 32 + i) * 33 + pp];
        hsum += __shfl_xor(hsum, 32, 64);
        if (half == 0) h_s[wv][pp] = hsum;
    }
    __syncthreads();

    float4 h4[8];
    #pragma unroll
    for (int i = 0; i < 8; ++i) h4[i] = *(const float4*)&h_s[wv][i * 4];

    float sc0, sc1, sc2, sc3;
    {
        float sv[4];
        #pragma unroll
        for (int c = 0; c < 4; ++c) {
            const float4* kr = (const float4*)(keys + (size_t)(c * 64 + lane) * PDIM);
            float a = 0.f;
            #pragma unroll
            for (int i = 0; i < 8; ++i) {
                const float4 k4 = kr[i];
                a = fmaf(k4.x, h4[i].x, a); a = fmaf(k4.y, h4[i].y, a);
                a = fmaf(k4.z, h4[i].z, a); a = fmaf(k4.w, h4[i].w, a);
            }
            sv[c] = a;
        }
        sc0 = sv[0]; sc1 = sv[1]; sc2 = sv[2]; sc3 = sv[3];
    }

    float wval[TOPK]; int widx[TOPK];
    #pragma unroll
    for (int r = 0; r < TOPK; ++r) {
        float bv = sc0; int bc = 0;
        if (sc1 > bv) { bv = sc1; bc = 1; }
        if (sc2 > bv) { bv = sc2; bc = 2; }
        if (sc3 > bv) { bv = sc3; bc = 3; }
        int bidx = bc * 64 + lane;
        #pragma unroll
        for (int off = 1; off < 64; off <<= 1) {
            const float ov = __shfl_xor(bv, off, 64);
            const int   oi = __shfl_xor(bidx, off, 64);
            if (ov > bv || (ov == bv && oi < bidx)) { bv = ov; bidx = oi; }
        }
        wval[r] = bv; widx[r] = bidx;
        if ((bidx & 63) == lane) {
            const int c = bidx >> 6;
            if (c == 0) sc0 = -FLT_MAX;
            else if (c == 1) sc1 = -FLT_MAX;
            else if (c == 2) sc2 = -FLT_MAX;
            else sc3 = -FLT_MAX;
        }
    }

    if (lane == 0 && traw < ntok) {
        float m = wval[0];
        #pragma unroll
        for (int k = 1; k < TOPK; ++k) m = fmaxf(m, wval[k]);
        float s = 0.f, e[TOPK];
        #pragma unroll
        for (int k = 0; k < TOPK; ++k) { e[k] = expf(wval[k] - m); s += e[k]; }
        #pragma unroll
        for (int k = 0; k < TOPK; ++k) {
            tki[tok * TOPK + k] = widx[k];
            tkw[tok * TOPK + k] = e[k] / s;
            atomicAdd(&gcount[widx[k]], 1);
        }
    }
}

// ---------------------------------------------------------------------------
// K1a (R12, validated): scan gcount -> offs, init gcur, tile list.
__global__ __launch_bounds__(NPAT) void scan_kernel(
    const int* __restrict__ gcount,
    int* __restrict__ offs,
    int* __restrict__ gcur,
    int* __restrict__ tile2p, int* __restrict__ tilei,
    int maxt)
{
    __shared__ int s[NPAT];
    const int tid = threadIdx.x;

    const int v = gcount[tid];
    s[tid] = v;
    __syncthreads();
    for (int off = 1; off < NPAT; off <<= 1) {
        int t = 0;
        if (tid >= off) t = s[tid - off];
        __syncthreads();
        s[tid] += t;
        __syncthreads();
    }
    const int incl = s[tid];
    offs[tid + 1] = incl;
    if (tid == 0) offs[0] = 0;
    gcur[tid] = incl - v;

    const int tc = (v + GT - 1) / GT;
    __syncthreads();
    s[tid] = tc;
    __syncthreads();
    for (int off = 1; off < NPAT; off <<= 1) {
        int t = 0;
        if (tid >= off) t = s[tid - off];
        __syncthreads();
        s[tid] += t;
        __syncthreads();
    }
    const int toff = s[tid] - tc;
    for (int i = tid; i < maxt; i += NPAT) tile2p[i] = -1;
    __syncthreads();
    for (int i = 0; i < tc; ++i) { tile2p[toff + i] = tid; tilei[toff + i] = i; }
}

// ---------------------------------------------------------------------------
// K1b (R12, validated): parallel CSR fill.
__global__ __launch_bounds__(BLOCK) void fill_kernel(
    const int* __restrict__ tki, const float* __restrict__ tkw,
    const float* __restrict__ scale_p,
    int* __restrict__ gcur,
    int* __restrict__ etok, float* __restrict__ ew, int* __restrict__ slotof,
    int nent)
{
    const int e = blockIdx.x * BLOCK + threadIdx.x;
    if (e >= nent) return;
    const int p = tki[e];
    const int slot = atomicAdd(&gcur[p], 1);
    etok[slot] = e >> 2;
    ew[slot]   = tkw[e] * scale_p[0];
    slotof[e]  = slot;
}

// ---------------------------------------------------------------------------
// K2 (R14): down-proj + silu + weight in ONE pass per half-tile.
// 8 tokens per block, grid = 2*maxt. Streams 8 vd chunks with
// double-buffered LDS (one barrier per chunk, global loads for c+1 issued
// before compute of c). x read directly from global (L1 broadcast).
// acc stays in registers across all chunks -> writes final projW (1 MB),
// no `part` round-trip.
__global__ __launch_bounds__(BLOCK, 4) void proj_kernel(
    const float* __restrict__ x,
    const float* __restrict__ vd,          // [NPAT, DDIM, PDIM]
    const int* __restrict__ offs,
    const int* __restrict__ etok,
    const float* __restrict__ ew,
    const int* __restrict__ tile2p,
    const int* __restrict__ tilei,
    float* __restrict__ projW,             // [nent+1][PDIM]
    int nent)
{
    __shared__ float vd_s[2][DCHP * PDIM]; // 2 x 16 KB
    __shared__ int   gt[HT];
    __shared__ float gw[HT];
    __shared__ int   gs[HT];

    const int tb = blockIdx.x >> 1;
    const int hf = blockIdx.x & 1;
    const int p  = tile2p[tb];
    if (p < 0) return;
    const int tid  = threadIdx.x;
    const int off0 = offs[p] + tilei[tb] * GT + hf * HT;
    const int gv   = min(HT, offs[p + 1] - off0);
    if (gv <= 0) return;                   // uniform per block, before barriers

    if (tid < HT) {
        if (tid < gv) { gt[tid] = etok[off0 + tid]; gw[tid] = ew[off0 + tid]; gs[tid] = off0 + tid; }
        else          { gt[tid] = etok[off0];       gw[tid] = 0.f;            gs[tid] = nent; }
    }

    const float* vdp = vd + (size_t)p * DDIM * PDIM;

    // prologue: stage chunk 0
    {
        const float4* vsrc = (const float4*)vdp;
        #pragma unroll
        for (int k = 0; k < 4; ++k)
            ((float4*)vd_s[0])[k * 256 + tid] = vsrc[k * 256 + tid];
    }
    __syncthreads();

    const int lane = tid & 63;
    const int wv   = tid >> 6;             // wave -> tokens wv*2, wv*2+1
    const int pp4  = lane & 7;
    const int seg  = lane >> 3;
    const int g0 = wv * 2, g1 = wv * 2 + 1;
    const float* xb0 = x + (size_t)gt[g0] * DDIM;
    const float* xb1 = x + (size_t)gt[g1] * DDIM;

    float4 acc0 = make_float4(0.f, 0.f, 0.f, 0.f);
    float4 acc1 = acc0;

    for (int c = 0; c < NCHP; ++c) {
        const int cur = c & 1;
        float4 st0, st1, st2, st3;
        if (c < NCHP - 1) {                // issue next-chunk loads early
            const float4* vsrc = (const float4*)(vdp + (size_t)(c + 1) * DCHP * PDIM);
            st0 = vsrc[0 * 256 + tid];
            st1 = vsrc[1 * 256 + tid];
            st2 = vsrc[2 * 256 + tid];
            st3 = vsrc[3 * 256 + tid];
        }

        #pragma unroll
        for (int i4 = 0; i4 < 4; ++i4) {
            const int d0 = seg * 16 + i4 * 4;
            const float* vb = &vd_s[cur][d0 * PDIM + pp4 * 4];
            const float4 v0 = *(const float4*)(vb + 0 * PDIM);
            const float4 v1 = *(const float4*)(vb + 1 * PDIM);
            const float4 v2 = *(const float4*)(vb + 2 * PDIM);
            const float4 v3 = *(const float4*)(vb + 3 * PDIM);
            const float4 xg0 = *(const float4*)(xb0 + c * DCHP + d0);
            const float4 xg1 = *(const float4*)(xb1 + c * DCHP + d0);

            acc0.x = fmaf(xg0.x, v0.x, acc0.x); acc0.y = fmaf(xg0.x, v0.y, acc0.y);
            acc0.z = fmaf(xg0.x, v0.z, acc0.z); acc0.w = fmaf(xg0.x, v0.w, acc0.w);
            acc0.x = fmaf(xg0.y, v1.x, acc0.x); acc0.y = fmaf(xg0.y, v1.y, acc0.y);
            acc0.z = fmaf(xg0.y, v1.z, acc0.z); acc0.w = fmaf(xg0.y, v1.w, acc0.w);
            acc0.x = fmaf(xg0.z, v2.x, acc0.x); acc0.y = fmaf(xg0.z, v2.y, acc0.y);
            acc0.z = fmaf(xg0.z, v2.z, acc0.z); acc0.w = fmaf(xg0.z, v2.w, acc0.w);
            acc0.x = fmaf(xg0.w, v3.x, acc0.x); acc0.y = fmaf(xg0.w, v3.y, acc0.y);
            acc0.z = fmaf(xg0.w, v3.z, acc0.z); acc0.w = fmaf(xg0.w, v3.w, acc0.w);

            acc1.x = fmaf(xg1.x, v0.x, acc1.x); acc1.y = fmaf(xg1.x, v0.y, acc1.y);
            acc1.z = fmaf(xg1.x, v0.z, acc1.z); acc1.w = fmaf(xg1.x, v0.w, acc1.w);
            acc1.x = fmaf(xg1.y, v1.x, acc1.x); acc1.y = fmaf(xg1.y, v1.y, acc1.y);
            acc1.z = fmaf(xg1.y, v1.z, acc1.z); acc1.w = fmaf(xg1.y, v1.w, acc1.w);
            acc1.x = fmaf(xg1.z, v2.x, acc1.x); acc1.y = fmaf(xg1.z, v2.y, acc1.y);
            acc1.z = fmaf(xg1.z, v2.z, acc1.z); acc1.w = fmaf(xg1.z, v2.w, acc1.w);
            acc1.x = fmaf(xg1.w, v3.x, acc1.x); acc1.y = fmaf(xg1.w, v3.y, acc1.y);
            acc1.z = fmaf(xg1.w, v3.z, acc1.z); acc1.w = fmaf(xg1.w, v3.w, acc1.w);
        }

        if (c < NCHP - 1) {
            const int nxt = cur ^ 1;       // write next chunk (other buffer)
            ((float4*)vd_s[nxt])[0 * 256 + tid] = st0;
            ((float4*)vd_s[nxt])[1 * 256 + tid] = st1;
            ((float4*)vd_s[nxt])[2 * 256 + tid] = st2;
            ((float4*)vd_s[nxt])[3 * 256 + tid] = st3;
            __syncthreads();               // one barrier per chunk
        }
    }

    // reduce over 8 segs; seg==0 lanes hold full-D dot for both tokens
    #pragma unroll
    for (int off = 8; off <= 32; off <<= 1) {
        acc0.x += __shfl_xor(acc0.x, off, 64);
        acc0.y += __shfl_xor(acc0.y, off, 64);
        acc0.z += __shfl_xor(acc0.z, off, 64);
        acc0.w += __shfl_xor(acc0.w, off, 64);
        acc1.x += __shfl_xor(acc1.x, off, 64);
        acc1.y += __shfl_xor(acc1.y, off, 64);
        acc1.z += __shfl_xor(acc1.z, off, 64);
        acc1.w += __shfl_xor(acc1.w, off, 64);
    }
    if ((lane & 0x38) == 0) {
        const float w0 = gw[g0], w1 = gw[g1];
        float4 o0, o1;
        o0.x = (acc0.x / (1.f + expf(-acc0.x))) * w0;
        o0.y = (acc0.y / (1.f + expf(-acc0.y))) * w0;
        o0.z = (acc0.z / (1.f + expf(-acc0.z))) * w0;
        o0.w = (acc0.w / (1.f + expf(-acc0.w))) * w0;
        o1.x = (acc1.x / (1.f + expf(-acc1.x))) * w1;
        o1.y = (acc1.y / (1.f + expf(-acc1.y))) * w1;
        o1.z = (acc1.z / (1.f + expf(-acc1.z))) * w1;
        o1.w = (acc1.w / (1.f + expf(-acc1.w))) * w1;
        *(float4*)&projW[(size_t)gs[g0] * PDIM + pp4 * 4] = o0;
        *(float4*)&projW[(size_t)gs[g1] * PDIM + pp4 * 4] = o1;
    }
}

// ---------------------------------------------------------------------------
// K3 (R14): up-projection, one (tile, 128-d chunk) per block (grid maxt*8,
// the validated high-occupancy R11 shape). Prologue now reads the final
// weighted projW (32 loads) instead of 8x32 part-sums + silu.
template <int MODE>
__global__ __launch_bounds__(BLOCK, 6) void up_kernel(
    const float* __restrict__ vu,          // [NPAT, PDIM, DDIM]
    const int* __restrict__ offs,
    const int* __restrict__ etok,
    const int* __restrict__ tile2p,
    const int* __restrict__ tilei,
    const float* __restrict__ projW,       // [nent+1][PDIM]
    float* __restrict__ dst,               // contrib (MODE 0) or out (MODE 1)
    int nent)
{
    __shared__ float vu_s[PDIM * DCHP];    // 16 KB
    __shared__ float projT[PDIM][20];
    __shared__ int   gt[GT];
    __shared__ int   gs[GT];

    const int tb  = blockIdx.x >> 3;
    const int c   = blockIdx.x & 7;
    const int p   = tile2p[tb];
    if (p < 0) return;
    const int tid = threadIdx.x;
    const int off0 = offs[p] + tilei[tb] * GT;
    const int gv   = min(GT, offs[p + 1] - off0);

    const float* vup = vu + (size_t)p * PDIM * DDIM + (size_t)c * DCHP;
    #pragma unroll
    for (int k = 0; k < 4; ++k) {
        const int q  = k * 256 + tid;
        const int pp = q >> 5, fi = q & 31;
        *(float4*)&vu_s[pp * DCHP + fi * 4] =
            *(const float4*)(vup + (size_t)pp * DDIM + fi * 4);
    }
    if (tid < GT) {
        if (tid < gv) { gt[tid] = etok[off0 + tid]; gs[tid] = off0 + tid; }
        else          { gt[tid] = etok[off0];       gs[tid] = nent; }
    }
    __syncthreads();

    #pragma unroll
    for (int r = 0; r < 2; ++r) {
        const int idx = tid + r * BLOCK;
        const int g = idx >> 5, pp = idx & 31;
        projT[pp][g] = projW[(size_t)gs[g] * PDIM + pp];
    }
    __syncthreads();

    const int tg  = tid >> 5;
    const int l32 = tid & 31;
    const int g0 = tg * 2, g1 = tg * 2 + 1;

    float4 o0 = make_float4(0.f, 0.f, 0.f, 0.f);
    float4 o1 = o0;
    #pragma unroll
    for (int pp = 0; pp < PDIM; ++pp) {
        const float4 vu4 = *(const float4*)&vu_s[pp * DCHP + l32 * 4];
        const float a = projT[pp][g0];
        const float b = projT[pp][g1];
        o0.x = fmaf(a, vu4.x, o0.x); o0.y = fmaf(a, vu4.y, o0.y);
        o0.z = fmaf(a, vu4.z, o0.z); o0.w = fmaf(a, vu4.w, o0.w);
        o1.x = fmaf(b, vu4.x, o1.x); o1.y = fmaf(b, vu4.y, o1.y);
        o1.z = fmaf(b, vu4.z, o1.z); o1.w = fmaf(b, vu4.w, o1.w);
    }

    if (MODE == 0) {
        *(float4*)(dst + (size_t)gs[g0] * DDIM + c * DCHP + l32 * 4) = o0;
        *(float4*)(dst + (size_t)gs[g1] * DDIM + c * DCHP + l32 * 4) = o1;
    } else {
        if (g0 < gv) {
            float* op = dst + (size_t)gt[g0] * DDIM + c * DCHP + l32 * 4;
            atomicAdd(op + 0, o0.x); atomicAdd(op + 1, o0.y);
            atomicAdd(op + 2, o0.z); atomicAdd(op + 3, o0.w);
        }
        if (g1 < gv) {
            float* op = dst + (size_t)gt[g1] * DDIM + c * DCHP + l32 * 4;
            atomicAdd(op + 0, o1.x); atomicAdd(op + 1, o1.y);
            atomicAdd(op + 2, o1.z); atomicAdd(op + 3, o1.w);
        }
    }
}

// ---------------------------------------------------------------------------
// K4: out[t] = x[t] + sum_k contrib[slotof[t][k]]  (verbatim-verified)
__global__ __launch_bounds__(BLOCK) void combine_kernel(
    const float* __restrict__ x, const float* __restrict__ contrib,
    const int* __restrict__ slotof, float* __restrict__ out)
{
    __shared__ int sl[TOPK];
    const int t = blockIdx.x, tid = threadIdx.x;
    if (tid < TOPK) sl[tid] = slotof[t * TOPK + tid];
    __syncthreads();
    float4 r = ((const float4*)(x + (size_t)t * DDIM))[tid];
    #pragma unroll
    for (int k = 0; k < TOPK; ++k) {
        const float4 cv = ((const float4*)(contrib + (size_t)sl[k] * DDIM))[tid];
        r.x += cv.x; r.y += cv.y; r.z += cv.z; r.w += cv.w;
    }
    ((float4*)(out + (size_t)t * DDIM))[tid] = r;
}

// ---------------------------------------------------------------------------
extern "C" void kernel_launch(void* const* d_in, const int* in_sizes, int n_in,
                              void* d_out, int out_size, void* d_ws, size_t ws_size,
                              hipStream_t stream) {
    const float* x        = (const float*)d_in[0];
    const float* hasher_w = (const float*)d_in[1];
    const float* keys     = (const float*)d_in[2];
    const float* vd       = (const float*)d_in[3];
    const float* vu       = (const float*)d_in[4];
    const float* scale    = (const float*)d_in[5];
    float* out = (float*)d_out;

    const int ntok = in_sizes[0] / DDIM;        // B*T
    if (ntok <= 0) return;
    const int nent = ntok * TOPK;
    const int maxt = (nent + GT - 1) / GT + NPAT;   // worst-case tile count

    // workspace layout
    char* w = (char*)d_ws;
    const size_t o_gcnt = 0;                                      // 256 int
    const size_t o_gcur = 1024;                                   // 256 int
    const size_t o_offs = 2048;                                   // 257 int
    const size_t o_tki  = 4096;                                   // nent int
    const size_t o_tkw  = o_tki  + (size_t)nent * 4;
    const size_t o_etok = o_tkw  + (size_t)nent * 4;
    const size_t o_ew   = o_etok + (size_t)nent * 4;
    const size_t o_slot = o_ew   + (size_t)nent * 4;
    const size_t o_t2p  = o_slot + (size_t)nent * 4;
    const size_t o_tli  = o_t2p  + (size_t)maxt * 4;
    const size_t o_pw   = (o_tli + (size_t)maxt * 4 + 255) & ~(size_t)255;
    const size_t pwsz   = (size_t)(nent + 1) * PDIM * 4;          // ~1 MB
    const size_t o_ctb  = (o_pw + pwsz + 255) & ~(size_t)255;
    const size_t needPW      = o_ctb;                              // atomic path
    const size_t needContrib = o_ctb + (size_t)(nent + 1) * DDIM * 4;

    int*   gcount = (int*)(w + o_gcnt);
    int*   gcur   = (int*)(w + o_gcur);
    int*   offs   = (int*)(w + o_offs);
    int*   tki    = (int*)(w + o_tki);
    float* tkw    = (float*)(w + o_tkw);
    int*   etok   = (int*)(w + o_etok);
    float* ew     = (float*)(w + o_ew);
    int*   slotof = (int*)(w + o_slot);
    int*   tile2p = (int*)(w + o_t2p);
    int*   tilei  = (int*)(w + o_tli);
    float* projW  = (float*)(w + o_pw);
    float* contrib= (float*)(w + o_ctb);

    hipMemsetAsync(gcount, 0, NPAT * sizeof(int), stream);

    const int rblocks = (ntok + RTPB - 1) / RTPB;
    hipLaunchKernelGGL(route_kernel, dim3(rblocks), dim3(BLOCK), 0, stream,
                       x, hasher_w, keys, tki, tkw, gcount, ntok);
    hipLaunchKernelGGL(scan_kernel, dim3(1), dim3(NPAT), 0, stream,
                       gcount, offs, gcur, tile2p, tilei, maxt);
    hipLaunchKernelGGL(fill_kernel, dim3((nent + BLOCK - 1) / BLOCK), dim3(BLOCK),
                       0, stream, tki, tkw, scale, gcur, etok, ew, slotof, nent);
    hipLaunchKernelGGL(proj_kernel, dim3(maxt * 2), dim3(BLOCK), 0, stream,
                       x, vd, offs, etok, ew, tile2p, tilei, projW, nent);

    if (ws_size >= needContrib) {
        hipLaunchKernelGGL((up_kernel<0>), dim3(maxt * 8), dim3(BLOCK), 0, stream,
                           vu, offs, etok, tile2p, tilei, projW, contrib, nent);
        hipLaunchKernelGGL(combine_kernel, dim3(ntok), dim3(BLOCK), 0, stream,
                           x, contrib, slotof, out);
    } else if (ws_size >= needPW) {
        hipMemcpyAsync(out, x, (size_t)ntok * DDIM * 4, hipMemcpyDeviceToDevice,
                       stream);
        hipLaunchKernelGGL((up_kernel<1>), dim3(maxt * 8), dim3(BLOCK), 0, stream,
                           vu, offs, etok, tile2p, tilei, projW, out, nent);
    }
}

// Round 8
// 197.443 us; speedup vs baseline: 1.0004x; 1.0004x over previous
//
#include <hip/hip_runtime.h>
#include <math.h>
#include <float.h>

#define DDIM 1024   // D
#define PDIM 32     // pattern_dim
#define NPAT 256    // n_patterns
#define TOPK 4
#define BLOCK 256
#define GT   16     // tokens per tile
#define DCHP 128    // d-chunk
#define NCHP 8      // d-chunks (DDIM/DCHP)
#define RTPB 8      // tokens per route block (2 per wave)

// ---------------------------------------------------------------------------
// K0 (R13/R6, correctness-validated): routing. 8 tokens/block, 2 per wave:
// hasher LDS staging and each ds_read of w4 amortized over 2 tokens.
__global__ __launch_bounds__(BLOCK) void route_kernel(
    const float* __restrict__ x,
    const float* __restrict__ hasher_w,   // [PDIM, DDIM]
    const float* __restrict__ keys,       // [NPAT, PDIM]
    int*   __restrict__ tki,              // [ntok, TOPK]
    float* __restrict__ tkw,              // [ntok, TOPK]
    int*   __restrict__ gcount,           // [NPAT], pre-zeroed
    int ntok)
{
    __shared__ float shmem[4 * 64 * 33];  // 33.8 KB dual-purpose
    __shared__ float h_s[4][2][PDIM];

    const int tid  = threadIdx.x;
    const int wv   = tid >> 6;
    const int lane = tid & 63;
    const int traw0 = blockIdx.x * RTPB + wv * 2;
    const int traw1 = traw0 + 1;
    const int tok0 = min(traw0, ntok - 1);
    const int tok1 = min(traw1, ntok - 1);

    float4 xr0[4], xr1[4];
    {
        const float4* p0 = (const float4*)(x + (size_t)tok0 * DDIM);
        const float4* p1 = (const float4*)(x + (size_t)tok1 * DDIM);
        #pragma unroll
        for (int i = 0; i < 4; ++i) { xr0[i] = p0[i * 64 + lane]; xr1[i] = p1[i * 64 + lane]; }
    }

    float part0[PDIM], part1[PDIM];
    #pragma unroll
    for (int pp = 0; pp < PDIM; ++pp) { part0[pp] = 0.f; part1[pp] = 0.f; }

    float* hs = shmem;                    // [32][256] per segment
    for (int i = 0; i < 4; ++i) {
        #pragma unroll
        for (int k = 0; k < 8; ++k) {
            const int q  = k * 256 + tid;
            const int pp = q >> 6, fi = q & 63;
            ((float4*)hs)[q] =
                *(const float4*)(hasher_w + (size_t)pp * DDIM + i * 256 + fi * 4);
        }
        __syncthreads();
        #pragma unroll
        for (int pp = 0; pp < PDIM; ++pp) {
            const float4 w4 = *(const float4*)&hs[pp * 256 + lane * 4];
            part0[pp] = fmaf(xr0[i].x, w4.x, part0[pp]);
            part0[pp] = fmaf(xr0[i].y, w4.y, part0[pp]);
            part0[pp] = fmaf(xr0[i].z, w4.z, part0[pp]);
            part0[pp] = fmaf(xr0[i].w, w4.w, part0[pp]);
            part1[pp] = fmaf(xr1[i].x, w4.x, part1[pp]);
            part1[pp] = fmaf(xr1[i].y, w4.y, part1[pp]);
            part1[pp] = fmaf(xr1[i].z, w4.z, part1[pp]);
            part1[pp] = fmaf(xr1[i].w, w4.w, part1[pp]);
        }
        __syncthreads();
    }

    float* P = shmem + wv * (64 * 33);
    #pragma unroll
    for (int t = 0; t < 2; ++t) {
        const float* part = t ? part1 : part0;
        #pragma unroll
        for (int pp = 0; pp < PDIM; ++pp) P[lane * 33 + pp] = part[pp];
        __syncthreads();
        {
            const int pp = lane & 31, half = lane >> 5;
            float hsum = 0.f;
            #pragma unroll 8
            for (int i = 0; i < 32; ++i)
                hsum += P[(half * 32 + i) * 33 + pp];
            hsum += __shfl_xor(hsum, 32, 64);
            if (half == 0) h_s[wv][t][pp] = hsum;
        }
        __syncthreads();
    }

    #pragma unroll
    for (int t = 0; t < 2; ++t) {
        const int traw = t ? traw1 : traw0;
        const int tok  = t ? tok1  : tok0;

        float4 h4[8];
        #pragma unroll
        for (int i = 0; i < 8; ++i) h4[i] = *(const float4*)&h_s[wv][t][i * 4];

        float sc0, sc1, sc2, sc3;
        {
            float sv[4];
            #pragma unroll
            for (int c = 0; c < 4; ++c) {
                const float4* kr = (const float4*)(keys + (size_t)(c * 64 + lane) * PDIM);
                float a = 0.f;
                #pragma unroll
                for (int i = 0; i < 8; ++i) {
                    const float4 k4 = kr[i];
                    a = fmaf(k4.x, h4[i].x, a); a = fmaf(k4.y, h4[i].y, a);
                    a = fmaf(k4.z, h4[i].z, a); a = fmaf(k4.w, h4[i].w, a);
                }
                sv[c] = a;
            }
            sc0 = sv[0]; sc1 = sv[1]; sc2 = sv[2]; sc3 = sv[3];
        }

        float wval[TOPK]; int widx[TOPK];
        #pragma unroll
        for (int r = 0; r < TOPK; ++r) {
            float bv = sc0; int bc = 0;
            if (sc1 > bv) { bv = sc1; bc = 1; }
            if (sc2 > bv) { bv = sc2; bc = 2; }
            if (sc3 > bv) { bv = sc3; bc = 3; }
            int bidx = bc * 64 + lane;
            #pragma unroll
            for (int off = 1; off < 64; off <<= 1) {
                const float ov = __shfl_xor(bv, off, 64);
                const int   oi = __shfl_xor(bidx, off, 64);
                if (ov > bv || (ov == bv && oi < bidx)) { bv = ov; bidx = oi; }
            }
            wval[r] = bv; widx[r] = bidx;
            if ((bidx & 63) == lane) {
                const int c = bidx >> 6;
                if (c == 0) sc0 = -FLT_MAX;
                else if (c == 1) sc1 = -FLT_MAX;
                else if (c == 2) sc2 = -FLT_MAX;
                else sc3 = -FLT_MAX;
            }
        }

        if (lane == 0 && traw < ntok) {
            float m = wval[0];
            #pragma unroll
            for (int k = 1; k < TOPK; ++k) m = fmaxf(m, wval[k]);
            float s = 0.f, e[TOPK];
            #pragma unroll
            for (int k = 0; k < TOPK; ++k) { e[k] = expf(wval[k] - m); s += e[k]; }
            #pragma unroll
            for (int k = 0; k < TOPK; ++k) {
                tki[tok * TOPK + k] = widx[k];
                tkw[tok * TOPK + k] = e[k] / s;
                atomicAdd(&gcount[widx[k]], 1);
            }
        }
    }
}

// ---------------------------------------------------------------------------
// K1a (R12, validated): scan gcount -> offs, init gcur, tile list.
__global__ __launch_bounds__(NPAT) void scan_kernel(
    const int* __restrict__ gcount,
    int* __restrict__ offs,
    int* __restrict__ gcur,
    int* __restrict__ tile2p, int* __restrict__ tilei,
    int maxt)
{
    __shared__ int s[NPAT];
    const int tid = threadIdx.x;

    const int v = gcount[tid];
    s[tid] = v;
    __syncthreads();
    for (int off = 1; off < NPAT; off <<= 1) {
        int t = 0;
        if (tid >= off) t = s[tid - off];
        __syncthreads();
        s[tid] += t;
        __syncthreads();
    }
    const int incl = s[tid];
    offs[tid + 1] = incl;
    if (tid == 0) offs[0] = 0;
    gcur[tid] = incl - v;

    const int tc = (v + GT - 1) / GT;
    __syncthreads();
    s[tid] = tc;
    __syncthreads();
    for (int off = 1; off < NPAT; off <<= 1) {
        int t = 0;
        if (tid >= off) t = s[tid - off];
        __syncthreads();
        s[tid] += t;
        __syncthreads();
    }
    const int toff = s[tid] - tc;
    for (int i = tid; i < maxt; i += NPAT) tile2p[i] = -1;
    __syncthreads();
    for (int i = 0; i < tc; ++i) { tile2p[toff + i] = tid; tilei[toff + i] = i; }
}

// ---------------------------------------------------------------------------
// K1b (R12, validated): parallel CSR fill.
__global__ __launch_bounds__(BLOCK) void fill_kernel(
    const int* __restrict__ tki, const float* __restrict__ tkw,
    const float* __restrict__ scale_p,
    int* __restrict__ gcur,
    int* __restrict__ etok, float* __restrict__ ew, int* __restrict__ slotof,
    int nent)
{
    const int e = blockIdx.x * BLOCK + threadIdx.x;
    if (e >= nent) return;
    const int p = tki[e];
    const int slot = atomicAdd(&gcur[p], 1);
    etok[slot] = e >> 2;
    ew[slot]   = tkw[e] * scale_p[0];
    slotof[e]  = slot;
}

// ---------------------------------------------------------------------------
// K2 (R11/R5, validated at 186 us): down-projection, one (tile, 128-d chunk)
// per block. Grid tb*8+c preserves chunk->XCD L2 affinity.
__global__ __launch_bounds__(BLOCK, 6) void proj_kernel(
    const float* __restrict__ x,
    const float* __restrict__ vd,          // [NPAT, DDIM, PDIM]
    const int* __restrict__ offs,
    const int* __restrict__ etok,
    const int* __restrict__ tile2p,
    const int* __restrict__ tilei,
    float* __restrict__ part,              // [NCHP][nent+1][PDIM]
    int nent)
{
    __shared__ float vd_s[DCHP * PDIM];    // 16 KB
    __shared__ float x_s[GT * DCHP];       // 8 KB
    __shared__ int   gt[GT];
    __shared__ int   gs[GT];

    const int tb  = blockIdx.x >> 3;
    const int c   = blockIdx.x & 7;
    const int p   = tile2p[tb];
    if (p < 0) return;
    const int tid = threadIdx.x;
    const int off0 = offs[p] + tilei[tb] * GT;
    const int gv   = min(GT, offs[p + 1] - off0);

    const float* vdp = vd + (size_t)p * DDIM * PDIM + (size_t)c * DCHP * PDIM;
    #pragma unroll
    for (int k = 0; k < 4; ++k)
        ((float4*)vd_s)[k * 256 + tid] = ((const float4*)vdp)[k * 256 + tid];

    if (tid < GT) {
        if (tid < gv) { gt[tid] = etok[off0 + tid]; gs[tid] = off0 + tid; }
        else          { gt[tid] = etok[off0];       gs[tid] = nent; }
    }
    __syncthreads();

    #pragma unroll
    for (int k = 0; k < 2; ++k) {
        const int q  = k * 256 + tid;
        const int g  = q >> 5, fi = q & 31;
        ((float4*)x_s)[g * 32 + fi] =
            *(const float4*)(x + (size_t)gt[g] * DDIM + c * DCHP + fi * 4);
    }
    __syncthreads();

    const int lane = tid & 63;
    const int wv   = tid >> 6;
    const int pp4  = lane & 7;
    const int seg  = lane >> 3;

    float4 acc[4];
    #pragma unroll
    for (int j = 0; j < 4; ++j) acc[j] = make_float4(0.f, 0.f, 0.f, 0.f);

    #pragma unroll
    for (int i4 = 0; i4 < 4; ++i4) {
        const int d0 = seg * 16 + i4 * 4;
        const float4 v0 = *(const float4*)&vd_s[(d0 + 0) * PDIM + pp4 * 4];
        const float4 v1 = *(const float4*)&vd_s[(d0 + 1) * PDIM + pp4 * 4];
        const float4 v2 = *(const float4*)&vd_s[(d0 + 2) * PDIM + pp4 * 4];
        const float4 v3 = *(const float4*)&vd_s[(d0 + 3) * PDIM + pp4 * 4];
        #pragma unroll
        for (int j = 0; j < 4; ++j) {
            const float4 xg = *(const float4*)&x_s[(wv * 4 + j) * DCHP + d0];
            acc[j].x = fmaf(xg.x, v0.x, acc[j].x);
            acc[j].y = fmaf(xg.x, v0.y, acc[j].y);
            acc[j].z = fmaf(xg.x, v0.z, acc[j].z);
            acc[j].w = fmaf(xg.x, v0.w, acc[j].w);
            acc[j].x = fmaf(xg.y, v1.x, acc[j].x);
            acc[j].y = fmaf(xg.y, v1.y, acc[j].y);
            acc[j].z = fmaf(xg.y, v1.z, acc[j].z);
            acc[j].w = fmaf(xg.y, v1.w, acc[j].w);
            acc[j].x = fmaf(xg.z, v2.x, acc[j].x);
            acc[j].y = fmaf(xg.z, v2.y, acc[j].y);
            acc[j].z = fmaf(xg.z, v2.z, acc[j].z);
            acc[j].w = fmaf(xg.z, v2.w, acc[j].w);
            acc[j].x = fmaf(xg.w, v3.x, acc[j].x);
            acc[j].y = fmaf(xg.w, v3.y, acc[j].y);
            acc[j].z = fmaf(xg.w, v3.z, acc[j].z);
            acc[j].w = fmaf(xg.w, v3.w, acc[j].w);
        }
    }

    #pragma unroll
    for (int j = 0; j < 4; ++j) {
        #pragma unroll
        for (int off = 8; off <= 32; off <<= 1) {
            acc[j].x += __shfl_xor(acc[j].x, off, 64);
            acc[j].y += __shfl_xor(acc[j].y, off, 64);
            acc[j].z += __shfl_xor(acc[j].z, off, 64);
            acc[j].w += __shfl_xor(acc[j].w, off, 64);
        }
    }

    float* partc = part + (size_t)c * (size_t)(nent + 1) * PDIM;
    if ((lane & 0x38) == 0) {
        #pragma unroll
        for (int j = 0; j < 4; ++j)
            *(float4*)&partc[(size_t)gs[wv * 4 + j] * PDIM + pp4 * 4] = acc[j];
    }
}

// ---------------------------------------------------------------------------
// K2b (R15, NEW): tiny pass — projW[r] = silu(sum_c part[c][r]) * ew[r].
// 9.4 MB traffic, ~3 us. Removes the 8-way part re-read + silu recompute
// from every up block. Row nent (padding) gets weight 0.
__global__ __launch_bounds__(BLOCK) void silu_kernel(
    const float* __restrict__ part,        // [NCHP][nent+1][PDIM]
    const float* __restrict__ ew,          // [nent]
    float* __restrict__ projW,             // [nent+1][PDIM]
    int nent)
{
    const int idx = blockIdx.x * BLOCK + threadIdx.x;
    const int total = (nent + 1) * PDIM;
    if (idx >= total) return;
    const int r = idx >> 5;
    const size_t PS = (size_t)(nent + 1) * PDIM;
    float s = 0.f;
    #pragma unroll
    for (int c = 0; c < NCHP; ++c) s += part[(size_t)c * PS + idx];
    const float w = (r < nent) ? ew[r] : 0.f;
    projW[idx] = (s / (1.f + expf(-s))) * w;
}

// ---------------------------------------------------------------------------
// K3 (R14 up, projW prologue; grid maxt*8 = validated high-occupancy shape).
template <int MODE>
__global__ __launch_bounds__(BLOCK, 6) void up_kernel(
    const float* __restrict__ vu,          // [NPAT, PDIM, DDIM]
    const int* __restrict__ offs,
    const int* __restrict__ etok,
    const int* __restrict__ tile2p,
    const int* __restrict__ tilei,
    const float* __restrict__ projW,       // [nent+1][PDIM]
    float* __restrict__ dst,               // contrib (MODE 0) or out (MODE 1)
    int nent)
{
    __shared__ float vu_s[PDIM * DCHP];    // 16 KB
    __shared__ float projT[PDIM][20];
    __shared__ int   gt[GT];
    __shared__ int   gs[GT];

    const int tb  = blockIdx.x >> 3;
    const int c   = blockIdx.x & 7;
    const int p   = tile2p[tb];
    if (p < 0) return;
    const int tid = threadIdx.x;
    const int off0 = offs[p] + tilei[tb] * GT;
    const int gv   = min(GT, offs[p + 1] - off0);

    const float* vup = vu + (size_t)p * PDIM * DDIM + (size_t)c * DCHP;
    #pragma unroll
    for (int k = 0; k < 4; ++k) {
        const int q  = k * 256 + tid;
        const int pp = q >> 5, fi = q & 31;
        *(float4*)&vu_s[pp * DCHP + fi * 4] =
            *(const float4*)(vup + (size_t)pp * DDIM + fi * 4);
    }
    if (tid < GT) {
        if (tid < gv) { gt[tid] = etok[off0 + tid]; gs[tid] = off0 + tid; }
        else          { gt[tid] = etok[off0];       gs[tid] = nent; }
    }
    __syncthreads();

    #pragma unroll
    for (int r = 0; r < 2; ++r) {
        const int idx = tid + r * BLOCK;
        const int g = idx >> 5, pp = idx & 31;
        projT[pp][g] = projW[(size_t)gs[g] * PDIM + pp];
    }
    __syncthreads();

    const int tg  = tid >> 5;
    const int l32 = tid & 31;
    const int g0 = tg * 2, g1 = tg * 2 + 1;

    float4 o0 = make_float4(0.f, 0.f, 0.f, 0.f);
    float4 o1 = o0;
    #pragma unroll
    for (int pp = 0; pp < PDIM; ++pp) {
        const float4 vu4 = *(const float4*)&vu_s[pp * DCHP + l32 * 4];
        const float a = projT[pp][g0];
        const float b = projT[pp][g1];
        o0.x = fmaf(a, vu4.x, o0.x); o0.y = fmaf(a, vu4.y, o0.y);
        o0.z = fmaf(a, vu4.z, o0.z); o0.w = fmaf(a, vu4.w, o0.w);
        o1.x = fmaf(b, vu4.x, o1.x); o1.y = fmaf(b, vu4.y, o1.y);
        o1.z = fmaf(b, vu4.z, o1.z); o1.w = fmaf(b, vu4.w, o1.w);
    }

    if (MODE == 0) {
        *(float4*)(dst + (size_t)gs[g0] * DDIM + c * DCHP + l32 * 4) = o0;
        *(float4*)(dst + (size_t)gs[g1] * DDIM + c * DCHP + l32 * 4) = o1;
    } else {
        if (g0 < gv) {
            float* op = dst + (size_t)gt[g0] * DDIM + c * DCHP + l32 * 4;
            atomicAdd(op + 0, o0.x); atomicAdd(op + 1, o0.y);
            atomicAdd(op + 2, o0.z); atomicAdd(op + 3, o0.w);
        }
        if (g1 < gv) {
            float* op = dst + (size_t)gt[g1] * DDIM + c * DCHP + l32 * 4;
            atomicAdd(op + 0, o1.x); atomicAdd(op + 1, o1.y);
            atomicAdd(op + 2, o1.z); atomicAdd(op + 3, o1.w);
        }
    }
}

// ---------------------------------------------------------------------------
// K4: out[t] = x[t] + sum_k contrib[slotof[t][k]]  (verbatim-verified)
__global__ __launch_bounds__(BLOCK) void combine_kernel(
    const float* __restrict__ x, const float* __restrict__ contrib,
    const int* __restrict__ slotof, float* __restrict__ out)
{
    __shared__ int sl[TOPK];
    const int t = blockIdx.x, tid = threadIdx.x;
    if (tid < TOPK) sl[tid] = slotof[t * TOPK + tid];
    __syncthreads();
    float4 r = ((const float4*)(x + (size_t)t * DDIM))[tid];
    #pragma unroll
    for (int k = 0; k < TOPK; ++k) {
        const float4 cv = ((const float4*)(contrib + (size_t)sl[k] * DDIM))[tid];
        r.x += cv.x; r.y += cv.y; r.z += cv.z; r.w += cv.w;
    }
    ((float4*)(out + (size_t)t * DDIM))[tid] = r;
}

// ---------------------------------------------------------------------------
extern "C" void kernel_launch(void* const* d_in, const int* in_sizes, int n_in,
                              void* d_out, int out_size, void* d_ws, size_t ws_size,
                              hipStream_t stream) {
    const float* x        = (const float*)d_in[0];
    const float* hasher_w = (const float*)d_in[1];
    const float* keys     = (const float*)d_in[2];
    const float* vd       = (const float*)d_in[3];
    const float* vu       = (const float*)d_in[4];
    const float* scale    = (const float*)d_in[5];
    float* out = (float*)d_out;

    const int ntok = in_sizes[0] / DDIM;        // B*T
    if (ntok <= 0) return;
    const int nent = ntok * TOPK;
    const int maxt = (nent + GT - 1) / GT + NPAT;   // worst-case tile count

    // workspace layout
    char* w = (char*)d_ws;
    const size_t o_gcnt = 0;                                      // 256 int
    const size_t o_gcur = 1024;                                   // 256 int
    const size_t o_offs = 2048;                                   // 257 int
    const size_t o_tki  = 4096;                                   // nent int
    const size_t o_tkw  = o_tki  + (size_t)nent * 4;
    const size_t o_etok = o_tkw  + (size_t)nent * 4;
    const size_t o_ew   = o_etok + (size_t)nent * 4;
    const size_t o_slot = o_ew   + (size_t)nent * 4;
    const size_t o_t2p  = o_slot + (size_t)nent * 4;
    const size_t o_tli  = o_t2p  + (size_t)maxt * 4;
    const size_t o_part = (o_tli + (size_t)maxt * 4 + 255) & ~(size_t)255;
    const size_t partsz = (size_t)NCHP * (size_t)(nent + 1) * PDIM * 4;
    const size_t o_pw   = (o_part + partsz + 255) & ~(size_t)255;
    const size_t pwsz   = (size_t)(nent + 1) * PDIM * 4;
    const size_t o_ctb  = (o_pw + pwsz + 255) & ~(size_t)255;
    const size_t needPW      = o_ctb;                              // atomic path
    const size_t needContrib = o_ctb + (size_t)(nent + 1) * DDIM * 4;

    int*   gcount = (int*)(w + o_gcnt);
    int*   gcur   = (int*)(w + o_gcur);
    int*   offs   = (int*)(w + o_offs);
    int*   tki    = (int*)(w + o_tki);
    float* tkw    = (float*)(w + o_tkw);
    int*   etok   = (int*)(w + o_etok);
    float* ew     = (float*)(w + o_ew);
    int*   slotof = (int*)(w + o_slot);
    int*   tile2p = (int*)(w + o_t2p);
    int*   tilei  = (int*)(w + o_tli);
    float* part   = (float*)(w + o_part);
    float* projW  = (float*)(w + o_pw);
    float* contrib= (float*)(w + o_ctb);

    hipMemsetAsync(gcount, 0, NPAT * sizeof(int), stream);

    const int rblocks = (ntok + RTPB - 1) / RTPB;
    hipLaunchKernelGGL(route_kernel, dim3(rblocks), dim3(BLOCK), 0, stream,
                       x, hasher_w, keys, tki, tkw, gcount, ntok);
    hipLaunchKernelGGL(scan_kernel, dim3(1), dim3(NPAT), 0, stream,
                       gcount, offs, gcur, tile2p, tilei, maxt);
    hipLaunchKernelGGL(fill_kernel, dim3((nent + BLOCK - 1) / BLOCK), dim3(BLOCK),
                       0, stream, tki, tkw, scale, gcur, etok, ew, slotof, nent);
    hipLaunchKernelGGL(proj_kernel, dim3(maxt * 8), dim3(BLOCK), 0, stream,
                       x, vd, offs, etok, tile2p, tilei, part, nent);
    hipLaunchKernelGGL(silu_kernel,
                       dim3(((nent + 1) * PDIM + BLOCK - 1) / BLOCK), dim3(BLOCK),
                       0, stream, part, ew, projW, nent);

    if (ws_size >= needContrib) {
        hipLaunchKernelGGL((up_kernel<0>), dim3(maxt * 8), dim3(BLOCK), 0, stream,
                           vu, offs, etok, tile2p, tilei, projW, contrib, nent);
        hipLaunchKernelGGL(combine_kernel, dim3(ntok), dim3(BLOCK), 0, stream,
                           x, contrib, slotof, out);
    } else if (ws_size >= needPW) {
        hipMemcpyAsync(out, x, (size_t)ntok * DDIM * 4, hipMemcpyDeviceToDevice,
                       stream);
        hipLaunchKernelGGL((up_kernel<1>), dim3(maxt * 8), dim3(BLOCK), 0, stream,
                           vu, offs, etok, tile2p, tilei, projW, out, nent);
    }
}

// Round 9
// 183.004 us; speedup vs baseline: 1.0794x; 1.0789x over previous
//
#include <hip/hip_runtime.h>
#include <math.h>
#include <float.h>

#define DDIM 1024   // D
#define PDIM 32     // pattern_dim
#define NPAT 256    // n_patterns
#define TOPK 4
#define BLOCK 256
#define GT   16     // tokens per tile
#define DCHP 128    // d-chunk
#define NCHP 8      // d-chunks (DDIM/DCHP)
#define RTPB 4      // tokens per route block (one per wave)

// ---------------------------------------------------------------------------
// K0 (R12, validated in the 186 us R5 run): routing, one WAVE per token,
// 4 tokens/block, 512 blocks. hasher_w staged in LDS per 256-d segment,
// lane-0 atomics into gcount.
__global__ __launch_bounds__(BLOCK) void route_kernel(
    const float* __restrict__ x,
    const float* __restrict__ hasher_w,   // [PDIM, DDIM]
    const float* __restrict__ keys,       // [NPAT, PDIM]
    int*   __restrict__ tki,              // [ntok, TOPK]
    float* __restrict__ tkw,              // [ntok, TOPK]
    int*   __restrict__ gcount,           // [NPAT], pre-zeroed
    int ntok)
{
    __shared__ float shmem[RTPB * 64 * 33];   // 33.8 KB dual-purpose
    __shared__ float h_s[RTPB][32];

    const int tid  = threadIdx.x;
    const int wv   = tid >> 6;
    const int lane = tid & 63;
    const int traw = blockIdx.x * RTPB + wv;
    const int tok  = min(traw, ntok - 1);

    const float4* xrow = (const float4*)(x + (size_t)tok * DDIM);
    float4 xr[4];
    #pragma unroll
    for (int i = 0; i < 4; ++i) xr[i] = xrow[i * 64 + lane];

    float part[PDIM];
    #pragma unroll
    for (int pp = 0; pp < PDIM; ++pp) part[pp] = 0.f;

    float* hs = shmem;
    for (int i = 0; i < 4; ++i) {
        #pragma unroll
        for (int k = 0; k < 8; ++k) {
            const int q  = k * 256 + tid;
            const int pp = q >> 6, fi = q & 63;
            ((float4*)hs)[q] =
                *(const float4*)(hasher_w + (size_t)pp * DDIM + i * 256 + fi * 4);
        }
        __syncthreads();
        #pragma unroll
        for (int pp = 0; pp < PDIM; ++pp) {
            const float4 w4 = *(const float4*)&hs[pp * 256 + lane * 4];
            part[pp] = fmaf(xr[i].x, w4.x, part[pp]);
            part[pp] = fmaf(xr[i].y, w4.y, part[pp]);
            part[pp] = fmaf(xr[i].z, w4.z, part[pp]);
            part[pp] = fmaf(xr[i].w, w4.w, part[pp]);
        }
        __syncthreads();
    }

    float* P = shmem + wv * (64 * 33);
    #pragma unroll
    for (int pp = 0; pp < PDIM; ++pp) P[lane * 33 + pp] = part[pp];
    __syncthreads();

    {
        const int pp = lane & 31, half = lane >> 5;
        float hsum = 0.f;
        #pragma unroll 8
        for (int i = 0; i < 32; ++i)
            hsum += P[(half * 32 + i) * 33 + pp];
        hsum += __shfl_xor(hsum, 32, 64);
        if (half == 0) h_s[wv][pp] = hsum;
    }
    __syncthreads();

    float4 h4[8];
    #pragma unroll
    for (int i = 0; i < 8; ++i) h4[i] = *(const float4*)&h_s[wv][i * 4];

    float sc0, sc1, sc2, sc3;
    {
        float sv[4];
        #pragma unroll
        for (int c = 0; c < 4; ++c) {
            const float4* kr = (const float4*)(keys + (size_t)(c * 64 + lane) * PDIM);
            float a = 0.f;
            #pragma unroll
            for (int i = 0; i < 8; ++i) {
                const float4 k4 = kr[i];
                a = fmaf(k4.x, h4[i].x, a); a = fmaf(k4.y, h4[i].y, a);
                a = fmaf(k4.z, h4[i].z, a); a = fmaf(k4.w, h4[i].w, a);
            }
            sv[c] = a;
        }
        sc0 = sv[0]; sc1 = sv[1]; sc2 = sv[2]; sc3 = sv[3];
    }

    float wval[TOPK]; int widx[TOPK];
    #pragma unroll
    for (int r = 0; r < TOPK; ++r) {
        float bv = sc0; int bc = 0;
        if (sc1 > bv) { bv = sc1; bc = 1; }
        if (sc2 > bv) { bv = sc2; bc = 2; }
        if (sc3 > bv) { bv = sc3; bc = 3; }
        int bidx = bc * 64 + lane;
        #pragma unroll
        for (int off = 1; off < 64; off <<= 1) {
            const float ov = __shfl_xor(bv, off, 64);
            const int   oi = __shfl_xor(bidx, off, 64);
            if (ov > bv || (ov == bv && oi < bidx)) { bv = ov; bidx = oi; }
        }
        wval[r] = bv; widx[r] = bidx;
        if ((bidx & 63) == lane) {
            const int c = bidx >> 6;
            if (c == 0) sc0 = -FLT_MAX;
            else if (c == 1) sc1 = -FLT_MAX;
            else if (c == 2) sc2 = -FLT_MAX;
            else sc3 = -FLT_MAX;
        }
    }

    if (lane == 0 && traw < ntok) {
        float m = wval[0];
        #pragma unroll
        for (int k = 1; k < TOPK; ++k) m = fmaxf(m, wval[k]);
        float s = 0.f, e[TOPK];
        #pragma unroll
        for (int k = 0; k < TOPK; ++k) { e[k] = expf(wval[k] - m); s += e[k]; }
        #pragma unroll
        for (int k = 0; k < TOPK; ++k) {
            tki[tok * TOPK + k] = widx[k];
            tkw[tok * TOPK + k] = e[k] / s;
            atomicAdd(&gcount[widx[k]], 1);
        }
    }
}

// ---------------------------------------------------------------------------
// K1a (R12, validated): scan gcount -> offs, init gcur, tile list.
__global__ __launch_bounds__(NPAT) void scan_kernel(
    const int* __restrict__ gcount,
    int* __restrict__ offs,
    int* __restrict__ gcur,
    int* __restrict__ tile2p, int* __restrict__ tilei,
    int maxt)
{
    __shared__ int s[NPAT];
    const int tid = threadIdx.x;

    const int v = gcount[tid];
    s[tid] = v;
    __syncthreads();
    for (int off = 1; off < NPAT; off <<= 1) {
        int t = 0;
        if (tid >= off) t = s[tid - off];
        __syncthreads();
        s[tid] += t;
        __syncthreads();
    }
    const int incl = s[tid];
    offs[tid + 1] = incl;
    if (tid == 0) offs[0] = 0;
    gcur[tid] = incl - v;

    const int tc = (v + GT - 1) / GT;
    __syncthreads();
    s[tid] = tc;
    __syncthreads();
    for (int off = 1; off < NPAT; off <<= 1) {
        int t = 0;
        if (tid >= off) t = s[tid - off];
        __syncthreads();
        s[tid] += t;
        __syncthreads();
    }
    const int toff = s[tid] - tc;
    for (int i = tid; i < maxt; i += NPAT) tile2p[i] = -1;
    __syncthreads();
    for (int i = 0; i < tc; ++i) { tile2p[toff + i] = tid; tilei[toff + i] = i; }
}

// ---------------------------------------------------------------------------
// K1b (R12, validated): parallel CSR fill.
__global__ __launch_bounds__(BLOCK) void fill_kernel(
    const int* __restrict__ tki, const float* __restrict__ tkw,
    const float* __restrict__ scale_p,
    int* __restrict__ gcur,
    int* __restrict__ etok, float* __restrict__ ew, int* __restrict__ slotof,
    int nent)
{
    const int e = blockIdx.x * BLOCK + threadIdx.x;
    if (e >= nent) return;
    const int p = tki[e];
    const int slot = atomicAdd(&gcur[p], 1);
    etok[slot] = e >> 2;
    ew[slot]   = tkw[e] * scale_p[0];
    slotof[e]  = slot;
}

// ---------------------------------------------------------------------------
// K2 (R11/R5, validated): down-projection, one (tile, 128-d chunk) per block.
// Grid tb*8+c preserves chunk->XCD L2 affinity.
__global__ __launch_bounds__(BLOCK, 6) void proj_kernel(
    const float* __restrict__ x,
    const float* __restrict__ vd,          // [NPAT, DDIM, PDIM]
    const int* __restrict__ offs,
    const int* __restrict__ etok,
    const int* __restrict__ tile2p,
    const int* __restrict__ tilei,
    float* __restrict__ part,              // [NCHP][nent+1][PDIM]
    int nent)
{
    __shared__ float vd_s[DCHP * PDIM];    // 16 KB
    __shared__ float x_s[GT * DCHP];       // 8 KB
    __shared__ int   gt[GT];
    __shared__ int   gs[GT];

    const int tb  = blockIdx.x >> 3;
    const int c   = blockIdx.x & 7;
    const int p   = tile2p[tb];
    if (p < 0) return;
    const int tid = threadIdx.x;
    const int off0 = offs[p] + tilei[tb] * GT;
    const int gv   = min(GT, offs[p + 1] - off0);

    const float* vdp = vd + (size_t)p * DDIM * PDIM + (size_t)c * DCHP * PDIM;
    #pragma unroll
    for (int k = 0; k < 4; ++k)
        ((float4*)vd_s)[k * 256 + tid] = ((const float4*)vdp)[k * 256 + tid];

    if (tid < GT) {
        if (tid < gv) { gt[tid] = etok[off0 + tid]; gs[tid] = off0 + tid; }
        else          { gt[tid] = etok[off0];       gs[tid] = nent; }
    }
    __syncthreads();

    #pragma unroll
    for (int k = 0; k < 2; ++k) {
        const int q  = k * 256 + tid;
        const int g  = q >> 5, fi = q & 31;
        ((float4*)x_s)[g * 32 + fi] =
            *(const float4*)(x + (size_t)gt[g] * DDIM + c * DCHP + fi * 4);
    }
    __syncthreads();

    const int lane = tid & 63;
    const int wv   = tid >> 6;
    const int pp4  = lane & 7;
    const int seg  = lane >> 3;

    float4 acc[4];
    #pragma unroll
    for (int j = 0; j < 4; ++j) acc[j] = make_float4(0.f, 0.f, 0.f, 0.f);

    #pragma unroll
    for (int i4 = 0; i4 < 4; ++i4) {
        const int d0 = seg * 16 + i4 * 4;
        const float4 v0 = *(const float4*)&vd_s[(d0 + 0) * PDIM + pp4 * 4];
        const float4 v1 = *(const float4*)&vd_s[(d0 + 1) * PDIM + pp4 * 4];
        const float4 v2 = *(const float4*)&vd_s[(d0 + 2) * PDIM + pp4 * 4];
        const float4 v3 = *(const float4*)&vd_s[(d0 + 3) * PDIM + pp4 * 4];
        #pragma unroll
        for (int j = 0; j < 4; ++j) {
            const float4 xg = *(const float4*)&x_s[(wv * 4 + j) * DCHP + d0];
            acc[j].x = fmaf(xg.x, v0.x, acc[j].x);
            acc[j].y = fmaf(xg.x, v0.y, acc[j].y);
            acc[j].z = fmaf(xg.x, v0.z, acc[j].z);
            acc[j].w = fmaf(xg.x, v0.w, acc[j].w);
            acc[j].x = fmaf(xg.y, v1.x, acc[j].x);
            acc[j].y = fmaf(xg.y, v1.y, acc[j].y);
            acc[j].z = fmaf(xg.y, v1.z, acc[j].z);
            acc[j].w = fmaf(xg.y, v1.w, acc[j].w);
            acc[j].x = fmaf(xg.z, v2.x, acc[j].x);
            acc[j].y = fmaf(xg.z, v2.y, acc[j].y);
            acc[j].z = fmaf(xg.z, v2.z, acc[j].z);
            acc[j].w = fmaf(xg.z, v2.w, acc[j].w);
            acc[j].x = fmaf(xg.w, v3.x, acc[j].x);
            acc[j].y = fmaf(xg.w, v3.y, acc[j].y);
            acc[j].z = fmaf(xg.w, v3.z, acc[j].z);
            acc[j].w = fmaf(xg.w, v3.w, acc[j].w);
        }
    }

    #pragma unroll
    for (int j = 0; j < 4; ++j) {
        #pragma unroll
        for (int off = 8; off <= 32; off <<= 1) {
            acc[j].x += __shfl_xor(acc[j].x, off, 64);
            acc[j].y += __shfl_xor(acc[j].y, off, 64);
            acc[j].z += __shfl_xor(acc[j].z, off, 64);
            acc[j].w += __shfl_xor(acc[j].w, off, 64);
        }
    }

    float* partc = part + (size_t)c * (size_t)(nent + 1) * PDIM;
    if ((lane & 0x38) == 0) {
        #pragma unroll
        for (int j = 0; j < 4; ++j)
            *(float4*)&partc[(size_t)gs[wv * 4 + j] * PDIM + pp4 * 4] = acc[j];
    }
}

// ---------------------------------------------------------------------------
// K2b (R15, kept): projW[r] = silu(sum_c part[c][r]) * ew[r]. ~9.4 MB, ~3 us.
__global__ __launch_bounds__(BLOCK) void silu_kernel(
    const float* __restrict__ part,        // [NCHP][nent+1][PDIM]
    const float* __restrict__ ew,          // [nent]
    float* __restrict__ projW,             // [nent+1][PDIM]
    int nent)
{
    const int idx = blockIdx.x * BLOCK + threadIdx.x;
    const int total = (nent + 1) * PDIM;
    if (idx >= total) return;
    const int r = idx >> 5;
    const size_t PS = (size_t)(nent + 1) * PDIM;
    float s = 0.f;
    #pragma unroll
    for (int c = 0; c < NCHP; ++c) s += part[(size_t)c * PS + idx];
    const float w = (r < nent) ? ew[r] : 0.f;
    projW[idx] = (s / (1.f + expf(-s))) * w;
}

// ---------------------------------------------------------------------------
// K3 (R14/R15 up, projW prologue; grid maxt*8).
template <int MODE>
__global__ __launch_bounds__(BLOCK, 6) void up_kernel(
    const float* __restrict__ vu,          // [NPAT, PDIM, DDIM]
    const int* __restrict__ offs,
    const int* __restrict__ etok,
    const int* __restrict__ tile2p,
    const int* __restrict__ tilei,
    const float* __restrict__ projW,       // [nent+1][PDIM]
    float* __restrict__ dst,               // contrib (MODE 0) or out (MODE 1)
    int nent)
{
    __shared__ float vu_s[PDIM * DCHP];    // 16 KB
    __shared__ float projT[PDIM][20];
    __shared__ int   gt[GT];
    __shared__ int   gs[GT];

    const int tb  = blockIdx.x >> 3;
    const int c   = blockIdx.x & 7;
    const int p   = tile2p[tb];
    if (p < 0) return;
    const int tid = threadIdx.x;
    const int off0 = offs[p] + tilei[tb] * GT;
    const int gv   = min(GT, offs[p + 1] - off0);

    const float* vup = vu + (size_t)p * PDIM * DDIM + (size_t)c * DCHP;
    #pragma unroll
    for (int k = 0; k < 4; ++k) {
        const int q  = k * 256 + tid;
        const int pp = q >> 5, fi = q & 31;
        *(float4*)&vu_s[pp * DCHP + fi * 4] =
            *(const float4*)(vup + (size_t)pp * DDIM + fi * 4);
    }
    if (tid < GT) {
        if (tid < gv) { gt[tid] = etok[off0 + tid]; gs[tid] = off0 + tid; }
        else          { gt[tid] = etok[off0];       gs[tid] = nent; }
    }
    __syncthreads();

    #pragma unroll
    for (int r = 0; r < 2; ++r) {
        const int idx = tid + r * BLOCK;
        const int g = idx >> 5, pp = idx & 31;
        projT[pp][g] = projW[(size_t)gs[g] * PDIM + pp];
    }
    __syncthreads();

    const int tg  = tid >> 5;
    const int l32 = tid & 31;
    const int g0 = tg * 2, g1 = tg * 2 + 1;

    float4 o0 = make_float4(0.f, 0.f, 0.f, 0.f);
    float4 o1 = o0;
    #pragma unroll
    for (int pp = 0; pp < PDIM; ++pp) {
        const float4 vu4 = *(const float4*)&vu_s[pp * DCHP + l32 * 4];
        const float a = projT[pp][g0];
        const float b = projT[pp][g1];
        o0.x = fmaf(a, vu4.x, o0.x); o0.y = fmaf(a, vu4.y, o0.y);
        o0.z = fmaf(a, vu4.z, o0.z); o0.w = fmaf(a, vu4.w, o0.w);
        o1.x = fmaf(b, vu4.x, o1.x); o1.y = fmaf(b, vu4.y, o1.y);
        o1.z = fmaf(b, vu4.z, o1.z); o1.w = fmaf(b, vu4.w, o1.w);
    }

    if (MODE == 0) {
        *(float4*)(dst + (size_t)gs[g0] * DDIM + c * DCHP + l32 * 4) = o0;
        *(float4*)(dst + (size_t)gs[g1] * DDIM + c * DCHP + l32 * 4) = o1;
    } else {
        if (g0 < gv) {
            float* op = dst + (size_t)gt[g0] * DDIM + c * DCHP + l32 * 4;
            atomicAdd(op + 0, o0.x); atomicAdd(op + 1, o0.y);
            atomicAdd(op + 2, o0.z); atomicAdd(op + 3, o0.w);
        }
        if (g1 < gv) {
            float* op = dst + (size_t)gt[g1] * DDIM + c * DCHP + l32 * 4;
            atomicAdd(op + 0, o1.x); atomicAdd(op + 1, o1.y);
            atomicAdd(op + 2, o1.z); atomicAdd(op + 3, o1.w);
        }
    }
}

// ---------------------------------------------------------------------------
// K4: out[t] = x[t] + sum_k contrib[slotof[t][k]]  (verbatim-verified)
__global__ __launch_bounds__(BLOCK) void combine_kernel(
    const float* __restrict__ x, const float* __restrict__ contrib,
    const int* __restrict__ slotof, float* __restrict__ out)
{
    __shared__ int sl[TOPK];
    const int t = blockIdx.x, tid = threadIdx.x;
    if (tid < TOPK) sl[tid] = slotof[t * TOPK + tid];
    __syncthreads();
    float4 r = ((const float4*)(x + (size_t)t * DDIM))[tid];
    #pragma unroll
    for (int k = 0; k < TOPK; ++k) {
        const float4 cv = ((const float4*)(contrib + (size_t)sl[k] * DDIM))[tid];
        r.x += cv.x; r.y += cv.y; r.z += cv.z; r.w += cv.w;
    }
    ((float4*)(out + (size_t)t * DDIM))[tid] = r;
}

// ---------------------------------------------------------------------------
extern "C" void kernel_launch(void* const* d_in, const int* in_sizes, int n_in,
                              void* d_out, int out_size, void* d_ws, size_t ws_size,
                              hipStream_t stream) {
    const float* x        = (const float*)d_in[0];
    const float* hasher_w = (const float*)d_in[1];
    const float* keys     = (const float*)d_in[2];
    const float* vd       = (const float*)d_in[3];
    const float* vu       = (const float*)d_in[4];
    const float* scale    = (const float*)d_in[5];
    float* out = (float*)d_out;

    const int ntok = in_sizes[0] / DDIM;        // B*T
    if (ntok <= 0) return;
    const int nent = ntok * TOPK;
    const int maxt = (nent + GT - 1) / GT + NPAT;   // worst-case tile count

    // workspace layout
    char* w = (char*)d_ws;
    const size_t o_gcnt = 0;                                      // 256 int
    const size_t o_gcur = 1024;                                   // 256 int
    const size_t o_offs = 2048;                                   // 257 int
    const size_t o_tki  = 4096;                                   // nent int
    const size_t o_tkw  = o_tki  + (size_t)nent * 4;
    const size_t o_etok = o_tkw  + (size_t)nent * 4;
    const size_t o_ew   = o_etok + (size_t)nent * 4;
    const size_t o_slot = o_ew   + (size_t)nent * 4;
    const size_t o_t2p  = o_slot + (size_t)nent * 4;
    const size_t o_tli  = o_t2p  + (size_t)maxt * 4;
    const size_t o_part = (o_tli + (size_t)maxt * 4 + 255) & ~(size_t)255;
    const size_t partsz = (size_t)NCHP * (size_t)(nent + 1) * PDIM * 4;
    const size_t o_pw   = (o_part + partsz + 255) & ~(size_t)255;
    const size_t pwsz   = (size_t)(nent + 1) * PDIM * 4;
    const size_t o_ctb  = (o_pw + pwsz + 255) & ~(size_t)255;
    const size_t needPW      = o_ctb;                              // atomic path
    const size_t needContrib = o_ctb + (size_t)(nent + 1) * DDIM * 4;

    int*   gcount = (int*)(w + o_gcnt);
    int*   gcur   = (int*)(w + o_gcur);
    int*   offs   = (int*)(w + o_offs);
    int*   tki    = (int*)(w + o_tki);
    float* tkw    = (float*)(w + o_tkw);
    int*   etok   = (int*)(w + o_etok);
    float* ew     = (float*)(w + o_ew);
    int*   slotof = (int*)(w + o_slot);
    int*   tile2p = (int*)(w + o_t2p);
    int*   tilei  = (int*)(w + o_tli);
    float* part   = (float*)(w + o_part);
    float* projW  = (float*)(w + o_pw);
    float* contrib= (float*)(w + o_ctb);

    hipMemsetAsync(gcount, 0, NPAT * sizeof(int), stream);

    const int rblocks = (ntok + RTPB - 1) / RTPB;
    hipLaunchKernelGGL(route_kernel, dim3(rblocks), dim3(BLOCK), 0, stream,
                       x, hasher_w, keys, tki, tkw, gcount, ntok);
    hipLaunchKernelGGL(scan_kernel, dim3(1), dim3(NPAT), 0, stream,
                       gcount, offs, gcur, tile2p, tilei, maxt);
    hipLaunchKernelGGL(fill_kernel, dim3((nent + BLOCK - 1) / BLOCK), dim3(BLOCK),
                       0, stream, tki, tkw, scale, gcur, etok, ew, slotof, nent);
    hipLaunchKernelGGL(proj_kernel, dim3(maxt * 8), dim3(BLOCK), 0, stream,
                       x, vd, offs, etok, tile2p, tilei, part, nent);
    hipLaunchKernelGGL(silu_kernel,
                       dim3(((nent + 1) * PDIM + BLOCK - 1) / BLOCK), dim3(BLOCK),
                       0, stream, part, ew, projW, nent);

    if (ws_size >= needContrib) {
        hipLaunchKernelGGL((up_kernel<0>), dim3(maxt * 8), dim3(BLOCK), 0, stream,
                           vu, offs, etok, tile2p, tilei, projW, contrib, nent);
        hipLaunchKernelGGL(combine_kernel, dim3(ntok), dim3(BLOCK), 0, stream,
                           x, contrib, slotof, out);
    } else if (ws_size >= needPW) {
        hipMemcpyAsync(out, x, (size_t)ntok * DDIM * 4, hipMemcpyDeviceToDevice,
                       stream);
        hipLaunchKernelGGL((up_kernel<1>), dim3(maxt * 8), dim3(BLOCK), 0, stream,
                           vu, offs, etok, tile2p, tilei, projW, out, nent);
    }
}